// Round 15
// baseline (53.619 us; speedup 1.0000x reference)
//
#include <hip/hip_runtime.h>
#include <math.h>

#define NN 50000
#define FD 128
#define HDIM 256
#define NE 800000
#define NBR_CAP 512
#define M_CAP 8192
#define TT 7
#define TPB 256
#define GB 96              // graph blocks: 96 x 12 = 1152 p-values
#define PSLICE 12
#define GRP 21             // gather groups per block (252 threads used)
#define ECHUNK 2048
#define SBLK 32            // stepper blocks (bid 96..127)
#define FGRID (GB + SBLK)  // fused grid = 128
#define SPIN_CAP 50000000

// ws offsets
#define O_NBRCNT   0       // zeroed by 64-B memset node
#define O_MCNT     64
#define O_GDONE    128     // GB u32 -> 512
#define O_HSYNC    512     // (TT+1)*HDIM u64 = 16384 -> 16896
#define O_DEG      16896   // NN f -> 216896
#define O_BITMAP   216896  // 1568 u32 -> 223168
#define O_ZERO_END 223168  // k_nbr zeroes [O_MCNT, O_ZERO_END)
#define O_NBRNODE  223168  // NBR_CAP i
#define O_NBRW     225216  // NBR_CAP f
#define O_MS       227264  // M_CAP i
#define O_MD       260032  // M_CAP i
#define O_MW       292800  // M_CAP f -> 325568
#define O_GPART    325568  // GB*1024 f -> 718784 (fully overwritten via ssf)

__device__ __forceinline__ float sigm(float v) { return 1.f / (1.f + expf(-v)); }
__device__ __forceinline__ float dis_of(float dg) {
    return dg > 0.f ? rsqrtf(fmaxf(dg, 1e-20f)) : 0.f;
}
// System-scope ops execute at the LLC: write-through stores, always-fresh loads.
__device__ __forceinline__ float slf(const float* p) {
    return __hip_atomic_load(p, __ATOMIC_RELAXED, __HIP_MEMORY_SCOPE_SYSTEM);
}
__device__ __forceinline__ void ssf(float* p, float v) {
    __hip_atomic_store(p, v, __ATOMIC_RELAXED, __HIP_MEMORY_SCOPE_SYSTEM);
}

// Scan 1: zero ctrl/hsync/deg/bitmap; collect nbr(0).
__global__ void k_nbr(const int* __restrict__ ei, const float* __restrict__ ew,
                      char* __restrict__ ws) {
    int*   nbrCnt = (int*)(ws + O_NBRCNT);
    int*   nbrNode= (int*)(ws + O_NBRNODE);
    float* nbrW   = (float*)(ws + O_NBRW);

    int gid = blockIdx.x * blockDim.x + threadIdx.x;
    if (gid < (O_ZERO_END - O_MCNT) / 4) ((unsigned*)(ws + O_MCNT))[gid] = 0u;

    int e0 = gid * 4;
    if (e0 >= NE) return;
    int4 d4 = *(const int4*)&ei[NE + e0];
    float4 w4 = *(const float4*)&ew[e0];
    int dd[4] = {d4.x, d4.y, d4.z, d4.w};
    float wv[4] = {w4.x, w4.y, w4.z, w4.w};
    #pragma unroll
    for (int k = 0; k < 4; ++k) {
        if (dd[k] == 0 && wv[k] != 0.f) {
            int s = ei[e0 + k];
            if (s != 0) {
                int slot = atomicAdd(nbrCnt, 1);
                if (slot < NBR_CAP) { nbrNode[slot] = s; nbrW[slot] = wv[k]; }
            }
        }
    }
}

// Scan 2: match edges with d==0 or d in nbr(0); record (s,d,w); mark needed nodes.
__global__ void k_match(const int* __restrict__ ei, const float* __restrict__ ew,
                        char* __restrict__ ws) {
    const int* nbrCnt = (const int*)(ws + O_NBRCNT);
    const int* nbrNode= (const int*)(ws + O_NBRNODE);
    int*      mCnt   = (int*)(ws + O_MCNT);
    int*      mS     = (int*)(ws + O_MS);
    int*      mD     = (int*)(ws + O_MD);
    float*    mW     = (float*)(ws + O_MW);
    unsigned* bitmap = (unsigned*)(ws + O_BITMAP);

    __shared__ int sNode[NBR_CAP];
    __shared__ int sCnt;
    if (threadIdx.x == 0) sCnt = min(*nbrCnt, NBR_CAP);
    __syncthreads();
    int cnt = sCnt;
    for (int i = threadIdx.x; i < cnt; i += blockDim.x) sNode[i] = nbrNode[i];
    __syncthreads();
    if (blockIdx.x == 0 && threadIdx.x == 0) atomicOr(&bitmap[0], 1u);

    int i = blockIdx.x * blockDim.x + threadIdx.x;
    int e0 = i * 4;
    if (e0 >= NE) return;
    int4 s4 = *(const int4*)&ei[e0];
    int4 d4 = *(const int4*)&ei[NE + e0];
    float4 w4 = *(const float4*)&ew[e0];
    int ss[4] = {s4.x, s4.y, s4.z, s4.w};
    int dd[4] = {d4.x, d4.y, d4.z, d4.w};
    float wv[4] = {w4.x, w4.y, w4.z, w4.w};
    bool m[4];
    #pragma unroll
    for (int k = 0; k < 4; ++k) m[k] = (dd[k] == 0);
    for (int j = 0; j < cnt; ++j) {
        int nv = sNode[j];
        #pragma unroll
        for (int k = 0; k < 4; ++k) m[k] |= (dd[k] == nv);
    }
    #pragma unroll
    for (int k = 0; k < 4; ++k) {
        int s = ss[k], d = dd[k];
        float w = wv[k];
        if (s == d || w == 0.f || !m[k]) continue;
        int slot = atomicAdd(mCnt, 1);
        if (slot < M_CAP) { mS[slot] = s; mD[slot] = d; mW[slot] = w; }
        atomicOr(&bitmap[s >> 5], 1u << (s & 31));
        atomicOr(&bitmap[d >> 5], 1u << (d & 31));
    }
}

// Scan 3: deg[s] += w only for bitmap-marked srcs.
__global__ void k_deg(const int* __restrict__ ei, const float* __restrict__ ew,
                      char* __restrict__ ws) {
    const unsigned* bitmap = (const unsigned*)(ws + O_BITMAP);
    float* deg = (float*)(ws + O_DEG);
    int i = blockIdx.x * blockDim.x + threadIdx.x;
    int e0 = i * 4;
    if (e0 >= NE) return;
    int4 s4 = *(const int4*)&ei[e0];
    int4 d4 = *(const int4*)&ei[NE + e0];
    float4 w4 = *(const float4*)&ew[e0];
    int ss[4] = {s4.x, s4.y, s4.z, s4.w};
    int dd[4] = {d4.x, d4.y, d4.z, d4.w};
    float wv[4] = {w4.x, w4.y, w4.z, w4.w};
    #pragma unroll
    for (int k = 0; k < 4; ++k) {
        int s = ss[k];
        if (s == dd[k] || wv[k] == 0.f) continue;
        if (bitmap[s >> 5] & (1u << (s & 31)))
            atomicAdd(&deg[s], wv[k]);
    }
}

// Fused graph + tail. 128 blocks x 256 thr.
// Blocks 0..95: graph slice (coef->gather->tslice->gemv) -> gpart (system stores)
//               -> release gdone[bid] -> exit.
// Blocks 96..127: steppers — load w_hh rows into VGPRs and poll gdone WHILE the
//               graph runs; then gpart reduce -> gates -> 7 exchange-synced steps.
__global__ __launch_bounds__(TPB) void k_fused(
    const float* __restrict__ x, const float* __restrict__ h, const float* __restrict__ c,
    const float* __restrict__ theta_x, const float* __restrict__ bias_x,
    const float* __restrict__ theta_h, const float* __restrict__ bias_h,
    const float* __restrict__ w_c, const float* __restrict__ b_gate,
    const float* __restrict__ w_ih, const float* __restrict__ w_hh,
    const float* __restrict__ b_ih, const float* __restrict__ b_hh,
    const float* __restrict__ w_out, const float* __restrict__ b_out,
    float* __restrict__ out, char* __restrict__ ws) {

    const float*        deg    = (const float*)(ws + O_DEG);
    const int*          nbrCnt = (const int*)(ws + O_NBRCNT);
    const int*          mCnt   = (const int*)(ws + O_MCNT);
    const int*          nbrNode= (const int*)(ws + O_NBRNODE);
    const float*        nbrW   = (const float*)(ws + O_NBRW);
    const int*          mS     = (const int*)(ws + O_MS);
    const int*          mD     = (const int*)(ws + O_MD);
    const float*        mW     = (const float*)(ws + O_MW);
    float*              gpart  = (float*)(ws + O_GPART);
    unsigned*           gdone  = (unsigned*)(ws + O_GDONE);
    unsigned long long* hsync  = (unsigned long long*)(ws + O_HSYNC);

    __shared__ int   sNode[NBR_CAP];
    __shared__ float sWl[NBR_CAP];
    __shared__ float cf1[ECHUNK], cf2[ECHUNK];
    __shared__ int   sS[ECHUNK];
    __shared__ float tp1[GRP][PSLICE], tp2[GRP][PSLICE];
    __shared__ float tslice[PSLICE];
    __shared__ __align__(16) float sh[HDIM];
    __shared__ float sdot[32];
    __shared__ float swsum[4];
    __shared__ int   sCnt, sMcnt;

    const int tid = threadIdx.x, bid = blockIdx.x;

    if (bid < GB) {
        // ================== graph block ==================
        if (tid == 0) { sCnt = min(*nbrCnt, NBR_CAP); sMcnt = min(*mCnt, M_CAP); }
        __syncthreads();
        const int ncnt = sCnt, mcnt = sMcnt;
        for (int i = tid; i < ncnt; i += TPB) { sNode[i] = nbrNode[i]; sWl[i] = nbrW[i]; }
        __syncthreads();

        const bool isx = bid < 32;                     // 384 x-rows, 768 h-rows
        const int qstart = bid * PSLICE - (isx ? 0 : 3 * FD);
        const float* fb0 = isx ? x : h;
        const int fstride = isx ? FD : HDIM;

        const int pl = tid % PSLICE, gr = tid / PSLICE;
        const float* fbase = fb0 + (qstart + pl) % fstride;
        const float dis0 = dis_of(deg[0]);

        float a1 = 0.f, a2 = 0.f;
        for (int c0i = 0; c0i < mcnt; c0i += ECHUNK) {
            int clen = min(ECHUNK, mcnt - c0i);
            for (int i = tid; i < clen; i += TPB) {    // inline per-edge coefs
                int sI = mS[c0i + i], dI = mD[c0i + i];
                float w = mW[c0i + i];
                float disd = dis_of(deg[dI]);
                float wn = dis_of(deg[sI]) * w * disd;
                float Wd = 0.f;
                for (int j = 0; j < ncnt; ++j) Wd += (sNode[j] == dI) ? sWl[j] : 0.f;
                cf1[i] = (dI == 0) ? wn : 0.f;
                cf2[i] = wn * (dis0 * disd * Wd);
                sS[i] = sI;
            }
            __syncthreads();
            if (gr < GRP) {                            // 4-deep pipelined gather
                int i = gr;
                for (; i + 3 * GRP < clen; i += 4 * GRP) {
                    int s0 = sS[i], s1 = sS[i + GRP], s2 = sS[i + 2 * GRP], s3 = sS[i + 3 * GRP];
                    float c10 = cf1[i], c11 = cf1[i + GRP], c12 = cf1[i + 2 * GRP], c13 = cf1[i + 3 * GRP];
                    float c20 = cf2[i], c21 = cf2[i + GRP], c22 = cf2[i + 2 * GRP], c23 = cf2[i + 3 * GRP];
                    float v0 = fbase[(size_t)s0 * fstride];
                    float v1 = fbase[(size_t)s1 * fstride];
                    float v2 = fbase[(size_t)s2 * fstride];
                    float v3 = fbase[(size_t)s3 * fstride];
                    a1 += c10 * v0 + c11 * v1 + c12 * v2 + c13 * v3;
                    a2 += c20 * v0 + c21 * v1 + c22 * v2 + c23 * v3;
                }
                for (; i < clen; i += GRP) {
                    float v = fbase[(size_t)sS[i] * fstride];
                    a1 += cf1[i] * v;
                    a2 += cf2[i] * v;
                }
            }
            __syncthreads();
        }
        if (gr < GRP) { tp1[gr][pl] = a1; tp2[gr][pl] = a2; }
        __syncthreads();
        if (tid < PSLICE) {
            float A1 = 0.f, A2 = 0.f;
            #pragma unroll
            for (int g2 = 0; g2 < GRP; ++g2) { A1 += tp1[g2][tid]; A2 += tp2[g2][tid]; }
            int q = qstart + tid;
            int ko = q / fstride;
            float ff0 = fb0[q % fstride];
            tslice[tid] = (ko == 0) ? ff0 : ((ko == 1) ? -A1 : 2.f * A2 - ff0);
        }
        __syncthreads();

        {   // gemv over the block's 12 p-rows; system-scope stores to gpart
            const float* tb = isx ? theta_x : theta_h;
            const size_t gs = isx ? (size_t)(3 * FD) * HDIM : (size_t)(3 * HDIM) * HDIM;
            float g0 = 0.f, g1 = 0.f, g2v = 0.f, g3 = 0.f;
            #pragma unroll
            for (int pp = 0; pp < PSLICE; ++pp) {
                float tv = tslice[pp];
                const float* row = tb + (size_t)(qstart + pp) * HDIM;
                g0  += tv * row[tid];
                g1  += tv * row[gs + tid];
                g2v += tv * row[2 * gs + tid];
                g3  += tv * row[3 * gs + tid];
            }
            float* gp = gpart + (size_t)bid * 1024;
            ssf(&gp[tid], g0);
            ssf(&gp[HDIM + tid], g1);
            ssf(&gp[2 * HDIM + tid], g2v);
            ssf(&gp[3 * HDIM + tid], g3);
        }
        __syncthreads();   // drains vmcnt: all this block's gpart stores at LLC
        if (tid == 0)
            __hip_atomic_store(&gdone[bid], 1u, __ATOMIC_RELEASE, __HIP_MEMORY_SCOPE_SYSTEM);
        return;
    }

    // ================== stepper block ==================
    const int sbid = bid - GB;

    // w_hh rows into VGPRs FIRST (overlaps graph compute; proven no-spill layout)
    const int rl = tid >> 3, seg = tid & 7;
    const int grow = (rl >> 3) * HDIM + sbid * 8 + (rl & 7);
    float4 wreg[8];
    #pragma unroll
    for (int k = 0; k < 8; ++k)
        wreg[k] = *(const float4*)&w_hh[(size_t)grow * HDIM + seg * 32 + k * 4];
    const float wih_r = w_ih[grow];
    const float br    = b_ih[grow] + b_hh[grow];
    const float bo    = b_out[0];
    const float wout_r = w_out[tid];

    // poll graph-done flags while the graph still runs (96 parallel pollers)
    if (tid < GB) {
        int sp = 0;
        while (__hip_atomic_load(&gdone[tid], __ATOMIC_RELAXED,
                                 __HIP_MEMORY_SCOPE_SYSTEM) == 0u) {
            if (++sp > SPIN_CAP) break;
        }
    }
    __syncthreads();       // all 96 flags observed -> all gpart data at LLC

    // gpart reduce for this block's 32 gate-dims: d = tid>>3, 8 threads/dim
    {
        const int d = tid >> 3, j = tid & 7;
        const int g = d >> 3, kk = d & 7, o = sbid * 8 + kk;
        float s = 0.f;
        #pragma unroll
        for (int pb = j; pb < GB; pb += 8) s += slf(&gpart[(size_t)pb * 1024 + g * HDIM + o]);
        s += __shfl_down(s, 4);
        s += __shfl_down(s, 2);
        s += __shfl_down(s, 1);
        if (j == 0) sdot[d] = s;
    }
    __syncthreads();

    // gates -> h0 store (tag 1); c0 in creg
    float creg = 0.f;
    if (tid < 8) {
        const int o = sbid * 8 + tid;
        float g0 = sdot[tid]      + bias_x[o]            + bias_h[o];
        float g1 = sdot[8 + tid]  + bias_x[HDIM + o]     + bias_h[HDIM + o];
        float g2 = sdot[16 + tid] + bias_x[2 * HDIM + o] + bias_h[2 * HDIM + o];
        float g3 = sdot[24 + tid] + bias_x[3 * HDIM + o] + bias_h[3 * HDIM + o];
        float c0 = c[o];
        float I  = sigm(g0 + w_c[o] * c0 + b_gate[o]);
        float Fg = sigm(g1 + w_c[HDIM + o] * c0 + b_gate[HDIM + o]);
        float Cn = Fg * c0 + I * tanhf(g2 + b_gate[2 * HDIM + o]);
        float O  = sigm(g3 + w_c[2 * HDIM + o] * Cn + b_gate[3 * HDIM + o]);
        float h0 = O * tanhf(Cn);
        creg = Cn;
        unsigned long long pk = (1ull << 32) | (unsigned long long)__float_as_uint(h0);
        __hip_atomic_store(&hsync[o], pk, __ATOMIC_RELAXED, __HIP_MEMORY_SCOPE_SYSTEM);
    }
    // parallel poll: every thread its own h0 word
    {
        unsigned long long v;
        int sp = 0;
        do {
            v = __hip_atomic_load(&hsync[tid], __ATOMIC_RELAXED, __HIP_MEMORY_SCOPE_SYSTEM);
            if ((unsigned)(v >> 32) == 1u) break;
        } while (++sp < SPIN_CAP);
        sh[tid] = __uint_as_float((unsigned)v);
    }
    __syncthreads();
    float sinp = x[FD - 1];

    for (int t = 0; t < TT; ++t) {
        // dot on sh = h(t)
        float acc = 0.f;
        const float* shh = &sh[seg * 32];
        #pragma unroll
        for (int k = 0; k < 8; ++k) {
            float4 hv = *(const float4*)&shh[k * 4];
            acc += hv.x * wreg[k].x + hv.y * wreg[k].y + hv.z * wreg[k].z + hv.w * wreg[k].w;
        }
        acc += __shfl_down(acc, 4);
        acc += __shfl_down(acc, 2);
        acc += __shfl_down(acc, 1);
        if (seg == 0) sdot[rl] = acc + sinp * wih_r + br;
        __syncthreads();                        // S1: sh reads done, sdot ready
        if (tid < 8) {
            float iv = sdot[tid], fv = sdot[8 + tid], gv = sdot[16 + tid], ov = sdot[24 + tid];
            float cn = sigm(fv) * creg + sigm(iv) * tanhf(gv);
            float hn = sigm(ov) * tanhf(cn);
            creg = cn;
            unsigned long long pk = (((unsigned long long)(t + 2)) << 32)
                                  | (unsigned long long)__float_as_uint(hn);
            __hip_atomic_store(&hsync[(t + 1) * HDIM + sbid * 8 + tid], pk,
                               __ATOMIC_RELAXED, __HIP_MEMORY_SCOPE_SYSTEM);
        }
        // parallel poll: every thread its own h(t+1) word; payload stays in reg
        float hval;
        {
            unsigned long long v;
            int sp = 0;
            do {
                v = __hip_atomic_load(&hsync[(t + 1) * HDIM + tid],
                                      __ATOMIC_RELAXED, __HIP_MEMORY_SCOPE_SYSTEM);
                if ((unsigned)(v >> 32) == (unsigned)(t + 2)) break;
            } while (++sp < SPIN_CAP);
            hval = __uint_as_float((unsigned)v);
        }
        sh[tid] = hval;
        float pw = wout_r * hval;               // register payload, no LDS wait
        pw += __shfl_down(pw, 32);
        pw += __shfl_down(pw, 16);
        pw += __shfl_down(pw, 8);
        pw += __shfl_down(pw, 4);
        pw += __shfl_down(pw, 2);
        pw += __shfl_down(pw, 1);
        if ((tid & 63) == 0) swsum[tid >> 6] = pw;
        __syncthreads();                        // S2: swsum + new sh visible
        float sval = swsum[0] + swsum[1] + swsum[2] + swsum[3] + bo;
        sinp = sval;                            // input to step t+1
        if (sbid == 0 && tid == 0) out[t] = sval;
    }
}

extern "C" void kernel_launch(void* const* d_in, const int* in_sizes, int n_in,
                              void* d_out, int out_size, void* d_ws, size_t ws_size,
                              hipStream_t stream) {
    const float* x       = (const float*)d_in[0];
    const int*   ei      = (const int*)d_in[1];
    const float* ew      = (const float*)d_in[2];
    const float* h       = (const float*)d_in[3];
    const float* c       = (const float*)d_in[4];
    const float* theta_x = (const float*)d_in[5];
    const float* bias_x  = (const float*)d_in[6];
    const float* theta_h = (const float*)d_in[7];
    const float* bias_h  = (const float*)d_in[8];
    const float* w_c     = (const float*)d_in[9];
    const float* b_gate  = (const float*)d_in[10];
    const float* w_ih    = (const float*)d_in[11];
    const float* w_hh    = (const float*)d_in[12];
    const float* b_ih    = (const float*)d_in[13];
    const float* b_hh    = (const float*)d_in[14];
    const float* w_out   = (const float*)d_in[15];
    const float* b_out   = (const float*)d_in[16];
    char* ws = (char*)d_ws;
    float* out = (float*)d_out;

    hipMemsetAsync(ws, 0, 64, stream);          // nbrCnt; rest zeroed by k_nbr

    int eb4 = (NE / 4 + TPB - 1) / TPB;         // 782 blocks
    k_nbr<<<eb4, TPB, 0, stream>>>(ei, ew, ws);
    k_match<<<eb4, TPB, 0, stream>>>(ei, ew, ws);
    k_deg<<<eb4, TPB, 0, stream>>>(ei, ew, ws);
    k_fused<<<FGRID, TPB, 0, stream>>>(x, h, c, theta_x, bias_x, theta_h, bias_h,
                                       w_c, b_gate, w_ih, w_hh, b_ih, b_hh,
                                       w_out, b_out, out, ws);
}